// Round 10
// baseline (111.717 us; speedup 1.0000x reference)
//
#include <hip/hip_runtime.h>
#include <hip/hip_bf16.h>
#include <stdint.h>

typedef __bf16 bf16;
typedef bf16 bf16x8 __attribute__((ext_vector_type(8)));
typedef bf16 bf16x4 __attribute__((ext_vector_type(4)));
typedef float f32x4 __attribute__((ext_vector_type(4)));

#define MFMA_16x16x32(a, b, c) __builtin_amdgcn_mfma_f32_16x16x32_bf16((a), (b), (c), 0, 0, 0)

// ---- problem sizes ----
constexpr int B = 16, S = 512, H = 768, NH = 12, DH = 64;
constexpr long NHID = (long)B * S * H;          // 6291456

// ---- workspace layout (bytes) ----
constexpr size_t XB_OFF = 0;
constexpr size_t XB_SZ  = (size_t)NHID * 2;                 // X bf16
constexpr size_t VT_OFF = XB_OFF + XB_SZ;                   // V^T: [B*NH][64][512] bf16
constexpr size_t VT_SZ  = (size_t)B * NH * DH * S * 2;
constexpr size_t QG_OFF = VT_OFF + VT_SZ;                   // Q: [B*NH][512][64] bf16
constexpr size_t QG_SZ  = (size_t)B * NH * S * DH * 2;
constexpr size_t WS_NEED = QG_OFF + QG_SZ;                  // ~36 MB

// ---------------- X-only f32 -> bf16 convert ----------------
__global__ void cvt_x(const float* __restrict__ src, bf16* __restrict__ dst) {
  long i = ((long)blockIdx.x * blockDim.x + threadIdx.x) * 8;
  if (i >= NHID) return;
  const float4* sp = reinterpret_cast<const float4*>(src + i);
  float4 a = sp[0], b = sp[1];
  bf16x8 o;
  o[0] = (bf16)a.x; o[1] = (bf16)a.y; o[2] = (bf16)a.z; o[3] = (bf16)a.w;
  o[4] = (bf16)b.x; o[5] = (bf16)b.y; o[6] = (bf16)b.z; o[7] = (bf16)b.w;
  *reinterpret_cast<bf16x8*>(dst + i) = o;
}

// ---------------- fused per-head projection + attention ----------------
// 192 blocks = one (b,h) head each, 512 threads = 8 waves, 1 block/CU.
// GEMM: three passes (V, Q, K), M=512 (64 rows/wave), N=64, BK=32, 24 steps.
//   A (X bf16): global_load_lds, 3 buffers, staged 2 ahead (R7-verified swizzle).
//   B (W f32):  global_load_lds, 4 buffers, staged 3 ahead; f32->bf16 during
//               fragment read (2x ds_read_b128 + cvt). 8-chunk XOR swizzle.
//   Boundary: s_waitcnt vmcnt(6); s_barrier  (A(t+2),B(t+2),B(t+3) in flight).
// V-pass epilogue -> global V^T [d][s]; Q-pass -> global Q [s][d];
// K-pass (last) -> K_lds (64KB, aliases A-staging region) with attn swizzle.
// Attention: per wave 64 q-rows (4 groups of 16); zero barriers; K from LDS,
// V^T/Q from L2-hot global; online softmax (verified R3 structure).
__global__ __launch_bounds__(512, 1) void fused_head(
    const bf16* __restrict__ Xb,
    const float* __restrict__ Wq, const float* __restrict__ Wk, const float* __restrict__ Wv,
    const float* __restrict__ bq, const float* __restrict__ bk, const float* __restrict__ bv,
    const int* __restrict__ eidx, const float* __restrict__ mask,
    bf16* __restrict__ VTg, bf16* __restrict__ Qg, float* __restrict__ out)
{
  __shared__ __align__(16) char smem[131072];
  bf16*  As   = (bf16*)smem;                    // 3 x 16384 elems (96 KB)
  float* Bsf  = (float*)(smem + 98304);         // 4 x 2048 elems (32 KB)
  bf16*  Ks   = (bf16*)smem;                    // alias: 512x64 (64 KB), post-GEMM
  float* maskS = (float*)(smem + 98304);        // alias B region, post-GEMM

  const int bid = blockIdx.x;
  const int xcd = bid & 7;
  const int j   = bid >> 3;                     // 0..23
  const int b   = xcd + ((j & 1) << 3);
  const int h   = j >> 1;
  const int bh  = b * NH + h;
  const int e   = eidx[b];

  const int tid = threadIdx.x, lane = tid & 63, wave = tid >> 6;
  const int r = lane & 15, lg = lane >> 4;

  // A staging (R7-verified): unit = 16 rows x 32 bf16 (1KB); 4 units/wave.
  const int srowA = lane >> 2;
  const int sgA = ((lane & 3) ^ ((lane >> 3) & 3)) * 8;    // bf16 elems
  const bf16* Abase = Xb + (size_t)b * S * H;
  // B staging: unit = 8 rows x 32 f32 (1KB); 1 unit/wave; slot c holds chunk c^srow.
  const int srowB = lane >> 3;                  // 0..7
  const int gBo = ((lane & 7) ^ srowB) * 4;     // f32 elems

  auto stageA = [&](int kt, int pb) {
    const int k0 = kt * 32;
#pragma unroll
    for (int i = 0; i < 4; ++i) {
      const int u = wave * 4 + i;               // 0..31
      const bf16* ga = Abase + (size_t)(u * 16 + srowA) * H + k0 + sgA;
      __builtin_amdgcn_global_load_lds(
          (const __attribute__((address_space(1))) void*)ga,
          (__attribute__((address_space(3))) void*)(As + pb * 16384 + u * 512), 16, 0, 0);
    }
  };
  auto stageB = [&](int kt, int pb, const float* Wsl) {
    const float* gb = Wsl + (size_t)(wave * 8 + srowB) * H + kt * 32 + gBo;
    __builtin_amdgcn_global_load_lds(
        (const __attribute__((address_space(1))) void*)gb,
        (__attribute__((address_space(3))) void*)(Bsf + pb * 2048 + wave * 256), 16, 0, 0);
  };

  const int sz = (r >> 1) & 3;                  // A read-side swizzle

  f32x4 acc[4][4];

  auto run_pass = [&](const float* Wsl) {
#pragma unroll
    for (int mi = 0; mi < 4; ++mi)
#pragma unroll
      for (int ni = 0; ni < 4; ++ni) acc[mi][ni] = (f32x4){0.f, 0.f, 0.f, 0.f};

    // prologue: A0,B0,A1,B1,B2 issued; keep newest 6 = {A1x4,B1,B2} in flight
    stageA(0, 0); stageB(0, 0, Wsl);
    stageA(1, 1); stageB(1, 1, Wsl); stageB(2, 2, Wsl);
    asm volatile("s_waitcnt vmcnt(6)\n\ts_barrier" ::: "memory");

#pragma unroll 1
    for (int t = 0; t < 24; ++t) {
      if (t + 2 < 24) stageA(t + 2, (t + 2) % 3);
      if (t + 3 < 24) stageB(t + 3, (t + 3) & 3, Wsl);

      const bf16* Ab = As + (t % 3) * 16384;
      const float* Bb = Bsf + (t & 3) * 2048;

      bf16x8 af[4], bfr[4];
#pragma unroll
      for (int mi = 0; mi < 4; ++mi)
        af[mi] = *reinterpret_cast<const bf16x8*>(
            &Ab[(wave * 64 + mi * 16 + r) * 32 + ((lg ^ sz) * 8)]);
#pragma unroll
      for (int ni = 0; ni < 4; ++ni) {
        const int row = ni * 16 + r;
        const int k7 = row & 7;
        f32x4 x0 = *reinterpret_cast<const f32x4*>(&Bb[row * 32 + (((lg * 2) ^ k7) * 4)]);
        f32x4 x1 = *reinterpret_cast<const f32x4*>(&Bb[row * 32 + ((((lg * 2) | 1) ^ k7) * 4)]);
        bf16x8 o;
        o[0] = (bf16)x0[0]; o[1] = (bf16)x0[1]; o[2] = (bf16)x0[2]; o[3] = (bf16)x0[3];
        o[4] = (bf16)x1[0]; o[5] = (bf16)x1[1]; o[6] = (bf16)x1[2]; o[7] = (bf16)x1[3];
        bfr[ni] = o;
      }
      __builtin_amdgcn_s_setprio(1);
#pragma unroll
      for (int mi = 0; mi < 4; ++mi)
#pragma unroll
        for (int ni = 0; ni < 4; ++ni)
          acc[mi][ni] = MFMA_16x16x32(af[mi], bfr[ni], acc[mi][ni]);
      __builtin_amdgcn_s_setprio(0);

      if (t < 20)
        asm volatile("s_waitcnt vmcnt(6)\n\ts_barrier" ::: "memory");
      else if (t < 23)
        asm volatile("s_waitcnt vmcnt(0)\n\ts_barrier" ::: "memory");
    }
    __syncthreads();   // full drain; all waves past final reads
  };

  // ---------------- pass 1: V -> global V^T ----------------
  run_pass(Wv + (size_t)e * H * H + (size_t)h * 64 * H);
  {
    bf16* vt = VTg + (size_t)bh * DH * S;
#pragma unroll
    for (int ni = 0; ni < 4; ++ni) {
      const int d = ni * 16 + r;
      const float bb = bv[(size_t)e * H + h * 64 + d];
#pragma unroll
      for (int mi = 0; mi < 4; ++mi) {
        bf16x4 v;
#pragma unroll
        for (int rr = 0; rr < 4; ++rr) v[rr] = (bf16)(acc[mi][ni][rr] + bb);
        *reinterpret_cast<bf16x4*>(&vt[(size_t)d * S + wave * 64 + mi * 16 + lg * 4]) = v;
      }
    }
  }

  // ---------------- pass 2: Q -> global Q [s][d] ----------------
  run_pass(Wq + (size_t)e * H * H + (size_t)h * 64 * H);
  {
    bf16* qg = Qg + (size_t)bh * S * DH;
#pragma unroll
    for (int ni = 0; ni < 4; ++ni) {
      const int d = ni * 16 + r;
      const float bb = bq[(size_t)e * H + h * 64 + d];
#pragma unroll
      for (int mi = 0; mi < 4; ++mi)
#pragma unroll
        for (int rr = 0; rr < 4; ++rr) {
          const int s = wave * 64 + mi * 16 + lg * 4 + rr;
          qg[(size_t)s * DH + d] = (bf16)(acc[mi][ni][rr] + bb);
        }
    }
  }

  // ---------------- pass 3: K -> K_lds (aliases A staging) ----------------
  run_pass(Wk + (size_t)e * H * H + (size_t)h * 64 * H);
  // run_pass ended with __syncthreads: all waves done reading As/Bsf.
  {
#pragma unroll
    for (int ni = 0; ni < 4; ++ni) {
      const int d = ni * 16 + r;
      const int c = d >> 3;
      const float bb = bk[(size_t)e * H + h * 64 + d];
#pragma unroll
      for (int mi = 0; mi < 4; ++mi)
#pragma unroll
        for (int rr = 0; rr < 4; ++rr) {
          const int krow = wave * 64 + mi * 16 + lg * 4 + rr;
          Ks[krow * 64 + ((c ^ (krow & 7)) * 8) + (d & 7)] = (bf16)(acc[mi][ni][rr] + bb);
        }
    }
    maskS[tid] = mask[b * S + tid];   // 512 threads = 512 values
  }
  __syncthreads();   // drains Ks ds_writes + all global stores (V^T, Q) to L2

  // ---------------- attention (no barriers) ----------------
  const bf16* qg = Qg + (size_t)bh * S * DH;
  const bf16* vt = VTg + (size_t)bh * DH * S;

  bf16x8 qf0[4], qf1[4];
#pragma unroll
  for (int g = 0; g < 4; ++g) {
    const bf16* qr = &qg[(size_t)(wave * 64 + g * 16 + r) * DH];
    qf0[g] = *reinterpret_cast<const bf16x8*>(qr + lg * 8);
    qf1[g] = *reinterpret_cast<const bf16x8*>(qr + 32 + lg * 8);
  }

  f32x4 ctx[4][4] = {};
  float mM[4] = {-3.0e38f, -3.0e38f, -3.0e38f, -3.0e38f};
  float lL[4] = {};

#pragma unroll 1
  for (int kt = 0; kt < 8; ++kt) {
    const int kb = kt * 64;
    // V fragments for this k-tile (L2-hot global), reused across 4 q-groups
    bf16x4 vlo[4][2], vhi[4][2];
#pragma unroll
    for (int dt = 0; dt < 4; ++dt)
#pragma unroll
      for (int kc = 0; kc < 2; ++kc) {
        const bf16* vr = &vt[(size_t)(dt * 16 + r) * S + kb + kc * 32 + lg * 4];
        vlo[dt][kc] = *reinterpret_cast<const bf16x4*>(vr);
        vhi[dt][kc] = *reinterpret_cast<const bf16x4*>(vr + 16);
      }

#pragma unroll
    for (int g = 0; g < 4; ++g) {
      f32x4 sa[4];
#pragma unroll
      for (int t = 0; t < 4; ++t) {
        const int row = kb + t * 16 + r;
        const int k7 = row & 7;
        bf16x8 kf0 = *reinterpret_cast<const bf16x8*>(&Ks[row * 64 + ((lg ^ k7) * 8)]);
        bf16x8 kf1 = *reinterpret_cast<const bf16x8*>(&Ks[row * 64 + (((lg + 4) ^ k7) * 8)]);
        f32x4 a = {};
        a = MFMA_16x16x32(kf0, qf0[g], a);
        a = MFMA_16x16x32(kf1, qf1[g], a);
        sa[t] = a;
      }
      // online softmax (lane's q = wave*64 + g*16 + r)
      float tmax = -3.0e38f;
#pragma unroll
      for (int t = 0; t < 4; ++t)
#pragma unroll
        for (int rr = 0; rr < 4; ++rr) {
          float s = sa[t][rr] * 0.125f + maskS[kb + t * 16 + lg * 4 + rr];
          sa[t][rr] = s;
          tmax = fmaxf(tmax, s);
        }
      tmax = fmaxf(tmax, __shfl_xor(tmax, 16));
      tmax = fmaxf(tmax, __shfl_xor(tmax, 32));
      const float mnew = fmaxf(mM[g], tmax);
      const float scale = __expf(mM[g] - mnew);
      mM[g] = mnew;
      float ps = 0.f;
#pragma unroll
      for (int t = 0; t < 4; ++t)
#pragma unroll
        for (int rr = 0; rr < 4; ++rr) {
          float p = __expf(sa[t][rr] - mnew);
          sa[t][rr] = p;
          ps += p;
        }
      lL[g] = lL[g] * scale + ps;
#pragma unroll
      for (int dt = 0; dt < 4; ++dt) ctx[g][dt] *= scale;

#pragma unroll
      for (int kc = 0; kc < 2; ++kc) {
        bf16x8 pf;
        f32x4 p0 = sa[2 * kc], p1 = sa[2 * kc + 1];
        pf[0] = (bf16)p0[0]; pf[1] = (bf16)p0[1]; pf[2] = (bf16)p0[2]; pf[3] = (bf16)p0[3];
        pf[4] = (bf16)p1[0]; pf[5] = (bf16)p1[1]; pf[6] = (bf16)p1[2]; pf[7] = (bf16)p1[3];
#pragma unroll
        for (int dt = 0; dt < 4; ++dt) {
          bf16x8 vf;
          bf16x4 lo = vlo[dt][kc], hi = vhi[dt][kc];
          vf[0] = lo[0]; vf[1] = lo[1]; vf[2] = lo[2]; vf[3] = lo[3];
          vf[4] = hi[0]; vf[5] = hi[1]; vf[6] = hi[2]; vf[7] = hi[3];
          ctx[g][dt] = MFMA_16x16x32(vf, pf, ctx[g][dt]);
        }
      }
    }
  }

#pragma unroll
  for (int g = 0; g < 4; ++g) {
    float l = lL[g];
    l += __shfl_xor(l, 16);
    l += __shfl_xor(l, 32);
    const float inv = 1.0f / l;
    float* obase = out + ((size_t)b * S + wave * 64 + g * 16 + r) * H + h * DH;
#pragma unroll
    for (int dt = 0; dt < 4; ++dt) {
      float4 o;
      o.x = ctx[g][dt][0] * inv; o.y = ctx[g][dt][1] * inv;
      o.z = ctx[g][dt][2] * inv; o.w = ctx[g][dt][3] * inv;
      *reinterpret_cast<float4*>(obase + dt * 16 + lg * 4) = o;
    }
  }
}

extern "C" void kernel_launch(void* const* d_in, const int* in_sizes, int n_in,
                              void* d_out, int out_size, void* d_ws, size_t ws_size,
                              hipStream_t stream) {
  const float* hidden = (const float*)d_in[0];
  const float* mask   = (const float*)d_in[1];
  const float* Wq = (const float*)d_in[2];
  const float* bq = (const float*)d_in[3];
  const float* Wk = (const float*)d_in[4];
  const float* bk = (const float*)d_in[5];
  const float* Wv = (const float*)d_in[6];
  const float* bv = (const float*)d_in[7];
  const int* eidx = (const int*)d_in[8];

  if (ws_size < WS_NEED) return;

  char* ws = (char*)d_ws;
  bf16* Xb  = (bf16*)(ws + XB_OFF);
  bf16* VTg = (bf16*)(ws + VT_OFF);
  bf16* Qg  = (bf16*)(ws + QG_OFF);
  float* out = (float*)d_out;

  cvt_x<<<3072, 256, 0, stream>>>(hidden, Xb);
  fused_head<<<192, 512, 0, stream>>>(Xb, Wq, Wk, Wv, bq, bk, bv, eidx, mask,
                                      VTg, Qg, out);
}